// Round 8
// baseline (408.766 us; speedup 1.0000x reference)
//
#include <hip/hip_runtime.h>
#include <hip/hip_bf16.h>
#include <math.h>

#define BB 32
#define LL 4096
#define HH 512
#define TM 64    // rows per block tile

typedef __attribute__((ext_vector_type(8))) short short8;
typedef __attribute__((ext_vector_type(8))) unsigned short u16x8;
typedef __attribute__((ext_vector_type(4))) float f32x4;

// manual RNE f32->bf16 (inputs are finite randn; no NaN path needed)
__device__ __forceinline__ unsigned short f2bf(float f) {
  unsigned int x;
  __builtin_memcpy(&x, &f, 4);
  x += 0x7fffu + ((x >> 16) & 1u);
  return (unsigned short)(x >> 16);
}
__device__ __forceinline__ float bf2f(unsigned short u) {
  unsigned int x = ((unsigned int)u) << 16;
  float f;
  __builtin_memcpy(&f, &x, 4);
  return f;
}
__device__ __forceinline__ float fast_tanh(float x) {
  float e = __expf(2.f * x);
  return 1.f - 2.f / (e + 1.f);
}

// ---------------------------------------------------------------------------
// prep: fused {base | wvf fragment pack}. grid 192, block 256
// wvf layout: [cb4(0..7)][kk(0..15)][n(0..3)][lane(0..63)][8] so the 4
// B-frags of one kk-step are contiguous (1 addr reg + imm offsets in main).
// frag f = (cb4*16+kk)*4+n holds Wv[(cb4*4+n)*16 + (lane&15)][kk*32+(lane>>4)*8 ..+8]
// ---------------------------------------------------------------------------
__global__ __launch_bounds__(256) void prep_kernel(
    const float* __restrict__ query, const float* __restrict__ Wq,
    const float* __restrict__ bias, const float* __restrict__ conv_b,
    const float* __restrict__ Wv, float* __restrict__ base,
    unsigned short* __restrict__ wvf) {
  const int bid = blockIdx.x;
  if (bid < 64) {
    const int b = bid >> 1;
    const int o = ((bid & 1) << 8) + threadIdx.x;
    __shared__ float qrow[HH];
    for (int i = threadIdx.x; i < HH; i += 256) qrow[i] = query[b * HH + i];
    __syncthreads();
    const float* wq = Wq + (size_t)o * HH;
    float acc = 0.f;
    for (int h = 0; h < HH; h += 4) {
      float4 w = *(const float4*)(wq + h);
      acc += w.x * qrow[h] + w.y * qrow[h + 1] + w.z * qrow[h + 2] + w.w * qrow[h + 3];
    }
    base[b * HH + o] = acc + bias[o] + conv_b[o];
  } else {
    const int chunk = (bid - 64) * 256 + threadIdx.x;
    const int l = chunk & 63;
    const int f = chunk >> 6;
    const int n = f & 3;
    const int kk = (f >> 2) & 15;
    const int cb4 = f >> 6;
    const int row = (cb4 * 4 + n) * 16 + (l & 15);
    const int colf = kk * 32 + (l >> 4) * 8;
    const float* src = Wv + (size_t)row * HH + colf;
    u16x8 v;
    #pragma unroll
    for (int j = 0; j < 8; ++j) v[j] = f2bf(src[j]);
    *(u16x8*)(wvf + (size_t)chunk * 8) = v;
  }
}

// ---------------------------------------------------------------------------
// main: block = (b, 64-row tile), 512 thr = 8 waves.
// Wave pairing for B-reuse: p = w>>1 owns col-quarter [p*128, p*128+128);
// rm = w&1 owns rows [rm*32, rm*32+32) (2 m-frags). The two waves of a
// pair issue IDENTICAL B addresses (L1 merge), and each B-frag feeds 2
// MFMAs in-reg -> per-CU L2 B-traffic halves vs round 7 and is L1-mergeable.
// Score partials kept in registers across the 2 col-chunks; one LDS
// scorered[4][64] combine at the end.
// grid (64, 32), block 512
// ---------------------------------------------------------------------------
__global__ __launch_bounds__(512, 4) void main_kernel(
    const float* __restrict__ value, const float* __restrict__ last_attn,
    const float* __restrict__ conv_w, const unsigned short* __restrict__ wvf,
    const float* __restrict__ Ws, const float* __restrict__ bs,
    const float* __restrict__ base, float* __restrict__ ctxp,
    float* __restrict__ attn) {
  const int b = blockIdx.y;
  const int gx = blockIdx.x;
  const int l0 = gx * TM;
  const int tid = threadIdx.x;
  const int w = tid >> 6;
  const int lane = tid & 63;
  const int g = lane >> 4;
  const int r16 = lane & 15;
  const int p = w >> 1;    // col-quarter
  const int rm = w & 1;    // row half

  __shared__ __align__(16) unsigned short A[TM * HH];  // 64 KiB, XOR-swizzled
  __shared__ float la_s[TM + 2];
  __shared__ float scorered[4][TM];
  __shared__ float srow[TM];
  __shared__ float ctxsum[HH];      // 2 KiB

  char* Ab = (char*)A;

  // ---- stage value tile: f32 -> bf16, swizzled LDS (8 chunks/thread) ----
  const float* vsrc = value + (size_t)(b * LL + l0) * HH;
  #pragma unroll
  for (int i = 0; i < 8; ++i) {
    const int c = tid + i * 512;
    const int row = c >> 6;
    const int cb = c & 63;
    const float4* s4 = (const float4*)(vsrc + (size_t)row * HH + cb * 8);
    float4 lo = s4[0], hi = s4[1];
    u16x8 v;
    v[0] = f2bf(lo.x); v[1] = f2bf(lo.y); v[2] = f2bf(lo.z); v[3] = f2bf(lo.w);
    v[4] = f2bf(hi.x); v[5] = f2bf(hi.y); v[6] = f2bf(hi.z); v[7] = f2bf(hi.w);
    const int off = row * 1024 + ((cb * 16) ^ ((row & 7) << 4));
    *(u16x8*)(Ab + off) = v;
  }
  ctxsum[tid] = 0.f;
  if (tid < TM + 2) {
    int l = l0 - 1 + tid;
    la_s[tid] = (l >= 0 && l < LL) ? last_attn[b * LL + l] : 0.f;
  }
  __syncthreads();

  // ---- preload la for this wave's 8 epilogue rows (2 m-frags x 6) ----
  float lav[2][6];
  #pragma unroll
  for (int m = 0; m < 2; ++m) {
    const int rbase = rm * 32 + m * 16 + g * 4;
    #pragma unroll
    for (int i = 0; i < 6; ++i) lav[m][i] = la_s[rbase + i];
  }

  // ---- K x N-chunk compute; score partials in regs ----
  float sp[2][4] = {};
  #pragma unroll 1
  for (int c = 0; c < 2; ++c) {
    // col constants for this 64-col chunk
    float basev[4], wsv[4], cw0v[4], cw1v[4], cw2v[4];
    #pragma unroll
    for (int n = 0; n < 4; ++n) {
      const int col = (p * 8 + c * 4 + n) * 16 + r16;
      basev[n] = base[b * HH + col];
      wsv[n]  = Ws[col];
      cw0v[n] = conv_w[col * 3 + 0];
      cw1v[n] = conv_w[col * 3 + 1];
      cw2v[n] = conv_w[col * 3 + 2];
    }

    f32x4 acc[2][4] = {};
    const short8* bbase = (const short8*)wvf + (size_t)(p * 2 + c) * 16 * 4 * 64;
    #pragma unroll
    for (int kk = 0; kk < 16; ++kk) {
      short8 bf0 = bbase[(kk * 4 + 0) * 64 + lane];
      short8 bf1 = bbase[(kk * 4 + 1) * 64 + lane];
      short8 bf2 = bbase[(kk * 4 + 2) * 64 + lane];
      short8 bf3 = bbase[(kk * 4 + 3) * 64 + lane];
      const int co = kk * 64 + g * 16;
      const int row0 = rm * 32 + r16;
      const int row1 = rm * 32 + 16 + r16;
      short8 a0 = *(const short8*)(Ab + row0 * 1024 + (co ^ ((row0 & 7) << 4)));
      short8 a1 = *(const short8*)(Ab + row1 * 1024 + (co ^ ((row1 & 7) << 4)));
      acc[0][0] = __builtin_amdgcn_mfma_f32_16x16x32_bf16(a0, bf0, acc[0][0], 0, 0, 0);
      acc[1][0] = __builtin_amdgcn_mfma_f32_16x16x32_bf16(a1, bf0, acc[1][0], 0, 0, 0);
      acc[0][1] = __builtin_amdgcn_mfma_f32_16x16x32_bf16(a0, bf1, acc[0][1], 0, 0, 0);
      acc[1][1] = __builtin_amdgcn_mfma_f32_16x16x32_bf16(a1, bf1, acc[1][1], 0, 0, 0);
      acc[0][2] = __builtin_amdgcn_mfma_f32_16x16x32_bf16(a0, bf2, acc[0][2], 0, 0, 0);
      acc[1][2] = __builtin_amdgcn_mfma_f32_16x16x32_bf16(a1, bf2, acc[1][2], 0, 0, 0);
      acc[0][3] = __builtin_amdgcn_mfma_f32_16x16x32_bf16(a0, bf3, acc[0][3], 0, 0, 0);
      acc[1][3] = __builtin_amdgcn_mfma_f32_16x16x32_bf16(a1, bf3, acc[1][3], 0, 0, 0);
    }

    // chunk epilogue: sp += tanh(acc + base + conv) * Ws
    #pragma unroll
    for (int m = 0; m < 2; ++m) {
      #pragma unroll
      for (int j = 0; j < 4; ++j) {
        float sum = 0.f;
        #pragma unroll
        for (int n = 0; n < 4; ++n) {
          float e = acc[m][n][j] + basev[n] +
                    cw0v[n] * lav[m][j] + cw1v[n] * lav[m][j + 1] + cw2v[n] * lav[m][j + 2];
          sum += fast_tanh(e) * wsv[n];
        }
        sp[m][j] += sum;
      }
    }
  }

  // ---- reduce sp over the 16 lanes of each col group ----
  #pragma unroll
  for (int m = 0; m < 2; ++m) {
    #pragma unroll
    for (int j = 0; j < 4; ++j) {
      float s = sp[m][j];
      s += __shfl_xor(s, 1, 64);
      s += __shfl_xor(s, 2, 64);
      s += __shfl_xor(s, 4, 64);
      s += __shfl_xor(s, 8, 64);
      if (r16 == 0) scorered[p][rm * 32 + m * 16 + g * 4 + j] = s;
    }
  }
  __syncthreads();

  if (tid < TM) {
    float sc = scorered[0][tid] + scorered[1][tid] + scorered[2][tid] +
               scorered[3][tid] + bs[0];
    float s = 1.f / (1.f + __expf(-sc));
    srow[tid] = s;
    attn[b * LL + l0 + tid] = s;   // unnormalized; finalize divides by S
  }
  __syncthreads();

  // ---- ctx partials: wave w rows [w*8, w*8+8), lane owns 8 cols ----
  {
    float cacc[8];
    #pragma unroll
    for (int k = 0; k < 8; ++k) cacc[k] = 0.f;
    #pragma unroll
    for (int i = 0; i < 8; ++i) {
      const int row = w * 8 + i;
      const float s = srow[row];
      const int off = row * 1024 + ((lane * 16) ^ ((row & 7) << 4));
      u16x8 v = *(const u16x8*)(Ab + off);
      #pragma unroll
      for (int k = 0; k < 8; ++k) cacc[k] += s * bf2f(v[k]);
    }
    #pragma unroll
    for (int k = 0; k < 8; ++k) atomicAdd(&ctxsum[lane * 8 + k], cacc[k]);
  }
  __syncthreads();
  atomicAdd(&ctxp[((size_t)(gx & 7) * BB + b) * HH + tid], ctxsum[tid]);
}

// ---------------------------------------------------------------------------
// finalize: per batch: S = sum_l s; attn /= S; out = [sum8(ctxp)/S, query]
// grid B, block 512
// ---------------------------------------------------------------------------
__global__ __launch_bounds__(512) void finalize_kernel(
    const float* __restrict__ query, const float* __restrict__ ctxp,
    float* __restrict__ out, float* __restrict__ attn) {
  const int b = blockIdx.x;
  const int tid = threadIdx.x;
  __shared__ float red[8];
  float s = 0.f;
  for (int l = tid; l < LL; l += 512) s += attn[b * LL + l];
  #pragma unroll
  for (int off = 32; off > 0; off >>= 1) s += __shfl_xor(s, off, 64);
  if ((tid & 63) == 0) red[tid >> 6] = s;
  __syncthreads();
  float S = 0.f;
  #pragma unroll
  for (int i = 0; i < 8; ++i) S += red[i];
  const float inv = 1.f / S;
  float c = 0.f;
  #pragma unroll
  for (int k = 0; k < 8; ++k) c += ctxp[((size_t)k * BB + b) * HH + tid];
  out[b * 2 * HH + tid] = c * inv;
  out[b * 2 * HH + HH + tid] = query[b * HH + tid];
  for (int l = tid; l < LL; l += 512) attn[b * LL + l] *= inv;
}

// ---------------------------------------------------------------------------
extern "C" void kernel_launch(void* const* d_in, const int* in_sizes, int n_in,
                              void* d_out, int out_size, void* d_ws, size_t ws_size,
                              hipStream_t stream) {
  const float* query     = (const float*)d_in[0];
  const float* value     = (const float*)d_in[1];
  const float* last_attn = (const float*)d_in[2];
  const float* conv_w    = (const float*)d_in[3];
  const float* conv_b    = (const float*)d_in[4];
  const float* Wq        = (const float*)d_in[5];
  const float* Wv        = (const float*)d_in[6];
  const float* Ws        = (const float*)d_in[7];
  const float* bs        = (const float*)d_in[8];
  const float* bias      = (const float*)d_in[9];

  float* out  = (float*)d_out;                 // (B, 2H)
  float* attn = out + BB * 2 * HH;             // (B, L)
  float* base = (float*)d_ws;                              // B*H f32
  unsigned short* wvf = (unsigned short*)(base + BB * HH); // 512*512 bf16
  float* ctxp = (float*)(wvf + HH * HH);                   // 8*B*H f32 partials

  hipMemsetAsync(ctxp, 0, 8 * BB * HH * sizeof(float), stream);
  prep_kernel<<<192, 256, 0, stream>>>(query, Wq, bias, conv_b, Wv, base, wvf);
  dim3 grid(LL / TM, BB);
  main_kernel<<<grid, 512, 0, stream>>>(value, last_attn, conv_w, wvf, Ws, bs,
                                        base, ctxp, attn);
  finalize_kernel<<<BB, 512, 0, stream>>>(query, ctxp, out, attn);
}